// Round 22
// baseline (79.809 us; speedup 1.0000x reference)
//
#include <hip/hip_runtime.h>
#include <stdint.h>

typedef unsigned long long u64;
typedef unsigned int u32;
typedef int v4i  __attribute__((ext_vector_type(4)));
typedef int v16i __attribute__((ext_vector_type(16)));

#define NUM_TRAIN   50000
#define NUM_TEST    4096
#define CLASS_SIZE  5000
#define TRAIN_PAD   50176              // 1568 tiles of 32 rows
#define TOT_TILES   1568

// ws layout: train_swz | test_i8 | te_sum | partial[c][col]
#define SZ_TRAIN   ((size_t)TRAIN_PAD * 256)          // 12,845,056 (= 1568 x 8KB)
#define SZ_TEST    ((size_t)NUM_TEST * 256)           //  1,048,576
#define SZ_TESUM   ((size_t)NUM_TEST * 4)             //     16,384
#define OFF_TEST   (SZ_TRAIN)
#define OFF_TESUM  (OFF_TEST + SZ_TEST)
#define OFF_PART   (OFF_TESUM + SZ_TESUM)             // 13,910,016
#define WS_NEED(NCH) (OFF_PART + (size_t)NUM_TEST * (NCH) * 3 * 4)

// ---------------------------------------------------------------------------
// Top-3 primitives. key = (dist<<16)+idx encodes the reference
// (dist asc, then smaller index) tie-break exactly (validated R2..R21).
// insert3 via v_med3_u32 (3 VALU) — validated on-device R15..R19/R21.
// ---------------------------------------------------------------------------
__device__ __forceinline__ void insert3(u32& k0, u32& k1, u32& k2, u32 key) {
    u32 m1, m2;
    asm("v_med3_u32 %0, %1, %2, %3" : "=v"(m1) : "v"(k0), "v"(k1), "v"(key));
    asm("v_med3_u32 %0, %1, %2, %3" : "=v"(m2) : "v"(k1), "v"(k2), "v"(key));
    k0 = min(k0, key);
    k1 = m1; k2 = m2;
}
__device__ __forceinline__ void merge3(u32& a0, u32& a1, u32& a2,
                                       u32 b0, u32 b1, u32 b2) {
    u32 hi0 = max(a0, b0);
    u32 lo1 = min(a1, b1);
    u32 c0  = min(a0, b0);
    u32 c1  = min(hi0, lo1);
    u32 c2  = min(max(lo1, hi0), min(a2, b2));
    a0 = c0; a1 = c1; a2 = c2;
}
__device__ __forceinline__ int wave_sum(int s) {
    #pragma unroll
    for (int off = 1; off < 64; off <<= 1) s += __shfl_xor(s, off);
    return s;
}
// Async global->LDS, 16B per lane. LDS dest = uniform base + lane*16;
// global src per-lane linear (base + lane*16). Validated R19.
__device__ __forceinline__ void gload16(const void* g, void* l) {
    __builtin_amdgcn_global_load_lds(
        (const __attribute__((address_space(1))) unsigned int*)g,
        (__attribute__((address_space(3))) unsigned int*)l, 16, 0, 0);
}

// ---------------------------------------------------------------------------
// pack_all (validated R19): train rows written PRE-SWIZZLED into the LDS
// target layout (T21 both-sides): within each 8KB tile, byte b of chunk
// (kk,kh,slot) at kk*1024+kh*512+slot*16+b holds A[row=slot^kk][kk*32+kh*16+b]
// so a LINEAR gload16 DMA reproduces the R10-validated conflict-free layout.
// Pad rows (>=50000) zero. Test rows: byte = 1-2*bit (+tesum).
// ---------------------------------------------------------------------------
__global__ __launch_bounds__(256) void pack_all(const int* __restrict__ train,
                                                const int* __restrict__ test,
                                                char* __restrict__ dstA,
                                                char* __restrict__ dstB,
                                                int* __restrict__ tesum) {
    int r    = (blockIdx.x * 256 + threadIdx.x) >> 6;
    int lane = threadIdx.x & 63;
    if (r < TRAIN_PAD) {
        int4 v = make_int4(0, 0, 0, 0);
        if (r < NUM_TRAIN)
            v = *reinterpret_cast<const int4*>(train + (size_t)r * 256 + lane * 4);
        u32 w = (u32)(v.x & 1) | ((u32)(v.y & 1) << 8)
              | ((u32)(v.z & 1) << 16) | ((u32)(v.w & 1) << 24);
        const int tile = r >> 5, row = r & 31;
        const int kk   = lane >> 3;
        const int kh   = (lane >> 2) & 1;
        const int slot = (row ^ kk) & 31;
        size_t dst = (size_t)tile * 8192 + kk * 1024 + kh * 512
                   + (size_t)slot * 16 + (lane & 3) * 4;
        *reinterpret_cast<u32*>(dstA + dst) = w;
    } else {
        int rt = r - TRAIN_PAD;
        int4 v = *reinterpret_cast<const int4*>(test + (size_t)rt * 256 + lane * 4);
        u32 w = (u32)((1 - 2 * v.x) & 0xFF) | ((u32)((1 - 2 * v.y) & 0xFF) << 8)
              | ((u32)((1 - 2 * v.z) & 0xFF) << 16) | ((u32)((1 - 2 * v.w) & 0xFF) << 24);
        *reinterpret_cast<u32*>(dstB + (size_t)rt * 256 + lane * 4) = w;
        int total = wave_sum(v.x + v.y + v.z + v.w);
        if (lane == 0) tesum[rt] = total;
    }
}

// ---------------------------------------------------------------------------
// mfma_knn (R22: 3-buffer rotating DMA pipeline, counted vmcnt, raw barrier):
//   Iter t: issue DMA tile t+2 -> buf[(t+2)%3]; compute tile t from buf[t%3];
//   s_waitcnt vmcnt(2) (own t+1 loads done, t+2's 2 stay IN FLIGHT across
//   the barrier); raw s_barrier. Steady state never drains vmcnt to 0 (T3/T4).
//   Hazards: per-wave vmcnt + barrier => tile t+1 fully landed for all waves;
//   buffer reuse (t+2 == t-1 mod 3) is WAR-safe because the DMA is issued
//   after barrier(t-1), which postdates all reads of that buffer.
//   In-loop VMEM ops are ONLY the 2 gload16/iter => exact counting.
//   Compute phase, layout, epilogue: byte-identical to validated R19.
// acc = tr_sum - 2*inner; dist = acc + te_sum folded into the key base.
// ---------------------------------------------------------------------------
template<int NCH>
__global__ __launch_bounds__(256) void mfma_knn(const char* __restrict__ A,
                                                const char* __restrict__ Bt,
                                                const int* __restrict__ tesum,
                                                u32* __restrict__ partial) {
    constexpr int TILES  = TOT_TILES / NCH;    // 14 (NCH=112)
    constexpr int CHROWS = TRAIN_PAD / NCH;    // 448
    static_assert((CHROWS & 31) == 0, "chunk must be whole tiles");
    const int cg   = blockIdx.x / NCH;
    const int c    = blockIdx.x % NCH;
    const int tid  = threadIdx.x;
    const int wid  = tid >> 6;
    const int lane = tid & 63;
    const int a    = lane & 31;                // A-row within tile / B-col lane
    const int kh   = lane >> 5;                // K-half

    // Two B-fragment sets: this wave's 64 test cols, 8 K-steps, in registers.
    const int col0 = cg * 256 + wid * 64 + a;
    const int col1 = col0 + 32;
    v4i bf0[8], bf1[8];
    {
        const char* bp0 = Bt + (size_t)col0 * 256 + kh * 16;
        const char* bp1 = Bt + (size_t)col1 * 256 + kh * 16;
        #pragma unroll
        for (int kk = 0; kk < 8; ++kk) {
            bf0[kk] = *reinterpret_cast<const v4i*>(bp0 + kk * 32);
            bf1[kk] = *reinterpret_cast<const v4i*>(bp1 + kk * 32);
        }
    }
    const u32 base0 = ((u32)tesum[col0] << 16);   // te_sum folded into key
    const u32 base1 = ((u32)tesum[col1] << 16);

    __shared__ char lds[3][8192];
    char* rd[8];                               // buf0 read addrs per kk
    #pragma unroll
    for (int kk = 0; kk < 8; ++kk)
        rd[kk] = &lds[0][kk * 1024 + kh * 512 + ((a ^ kk) & 31) * 16];

    // DMA staging: linear copy of pre-swizzled tile; wave wid covers
    // bytes [wid*2048, +2048) via two 1KB gload16 (per-lane src +lane*16).
    const char* asrc = A + (size_t)(c * (CHROWS / 32)) * 8192
                         + wid * 2048 + lane * 16;
    char* ldst = &lds[0][wid * 2048];

    u32 p00 = 0x7FFFFFFFu, p01 = 0x7FFFFFFFu, p02 = 0x7FFFFFFFu;
    u32 p10 = 0x7FFFFFFFu, p11 = 0x7FFFFFFFu, p12 = 0x7FFFFFFFu;

    // prologue: issue DMA tiles 0 (buf0) and 1 (buf1); wait tile 0 only.
    gload16(asrc,                &lds[0][wid * 2048]);
    gload16(asrc + 1024,         &lds[0][wid * 2048 + 1024]);
    gload16(asrc + 8192,         &lds[1][wid * 2048]);
    gload16(asrc + 8192 + 1024,  &lds[1][wid * 2048 + 1024]);
    asm volatile("s_waitcnt vmcnt(2)" ::: "memory");   // tile 0 landed
    __builtin_amdgcn_s_barrier();

    u32 roff = 0;          // read buffer byte offset  = (t%3)*8192
    u32 woff = 16384;      // write buffer byte offset = ((t+2)%3)*8192

    #pragma unroll 1
    for (int t = 0; t < TILES; ++t) {
        const bool issue = (t + 2 < TILES);
        if (issue) {
            const char* g = asrc + (size_t)(t + 2) * 8192;
            gload16(g,        ldst + woff);
            gload16(g + 1024, ldst + woff + 1024);
        }
        v16i acc0 = {0,0,0,0,0,0,0,0,0,0,0,0,0,0,0,0};
        v16i acc1 = {0,0,0,0,0,0,0,0,0,0,0,0,0,0,0,0};
        __builtin_amdgcn_s_setprio(1);
        #pragma unroll
        for (int kk = 0; kk < 8; ++kk) {
            v4i af = *reinterpret_cast<const v4i*>(rd[kk] + roff);
            acc0 = __builtin_amdgcn_mfma_i32_32x32x32_i8(af, bf0[kk], acc0, 0, 0, 0);
            acc1 = __builtin_amdgcn_mfma_i32_32x32x32_i8(af, bf1[kk], acc1, 0, 0, 0);
        }
        __builtin_amdgcn_s_setprio(0);
        const int tbase = c * CHROWS + t * 32;
        const u32 kb0 = base0 + (u32)(tbase + 4 * kh);
        const u32 kb1 = base1 + (u32)(tbase + 4 * kh);
        if (tbase + 32 <= NUM_TRAIN) {               // uniform fast path
            #pragma unroll
            for (int g = 0; g < 16; ++g) {
                const int row = (g & 3) + 8 * (g >> 2);
                insert3(p00, p01, p02, ((u32)acc0[g] << 16) + kb0 + (u32)row);
                insert3(p10, p11, p12, ((u32)acc1[g] << 16) + kb1 + (u32)row);
            }
        } else {                                     // boundary/pad tiles only
            #pragma unroll
            for (int g = 0; g < 16; ++g) {
                const int row = (g & 3) + 8 * (g >> 2);
                const int idx = tbase + 4 * kh + row;
                u32 key0 = (idx < NUM_TRAIN)
                             ? (((u32)acc0[g] << 16) + kb0 + (u32)row) : 0xFFFFFFFFu;
                u32 key1 = (idx < NUM_TRAIN)
                             ? (((u32)acc1[g] << 16) + kb1 + (u32)row) : 0xFFFFFFFFu;
                insert3(p00, p01, p02, key0);
                insert3(p10, p11, p12, key1);
            }
        }
        if (t + 1 < TILES) {
            if (issue) asm volatile("s_waitcnt vmcnt(2)" ::: "memory"); // t+1 landed, t+2 in flight
            else       asm volatile("s_waitcnt vmcnt(0)" ::: "memory"); // tail: drain
            __builtin_amdgcn_s_barrier();
        }
        roff = (roff == 16384) ? 0 : roff + 8192;
        woff = (woff == 16384) ? 0 : woff + 8192;
    }

    // lanes l / l+32 hold complementary row-halves of the same test col
    u32 o0, o1, o2;
    o0 = __shfl_xor(p00, 32); o1 = __shfl_xor(p01, 32); o2 = __shfl_xor(p02, 32);
    merge3(p00, p01, p02, o0, o1, o2);
    o0 = __shfl_xor(p10, 32); o1 = __shfl_xor(p11, 32); o2 = __shfl_xor(p12, 32);
    merge3(p10, p11, p12, o0, o1, o2);
    if (kh == 0) {
        // transposed layout: consecutive cols -> consecutive 12B (coalesced)
        u32* d0 = partial + ((size_t)c * NUM_TEST + col0) * 3;
        d0[0] = p00; d0[1] = p01; d0[2] = p02;
        u32* d1 = partial + ((size_t)c * NUM_TEST + col1) * 3;
        d1[0] = p10; d1[1] = p11; d1[2] = p12;
    }
}

// ---------------------------------------------------------------------------
// vote_knn16 (validated R21): 16 lanes per sample; each merges NCH/16 chunks,
// then 4 __shfl_xor merge3 steps. Majority vote, argmax-first-max ties.
// ---------------------------------------------------------------------------
template<int NCH>
__global__ __launch_bounds__(256) void vote_knn16(const u32* __restrict__ partial,
                                                  int* __restrict__ out) {
    static_assert(NCH % 16 == 0, "16-lane vote needs NCH % 16 == 0");
    const int gid = blockIdx.x * 256 + threadIdx.x;
    const int t   = gid >> 4;          // sample
    const int sub = gid & 15;          // 16-lane group index (= lane & 15)
    if (t >= NUM_TEST) return;
    u32 a0 = 0x7FFFFFFFu, a1 = 0x7FFFFFFFu, a2 = 0x7FFFFFFFu;
    #pragma unroll
    for (int j = 0; j < NCH / 16; ++j) {
        const int c = sub + 16 * j;
        const u32* q = partial + ((size_t)c * NUM_TEST + t) * 3;
        merge3(a0, a1, a2, q[0], q[1], q[2]);
    }
    #pragma unroll
    for (int off = 1; off < 16; off <<= 1) {
        u32 o0 = __shfl_xor(a0, off);
        u32 o1 = __shfl_xor(a1, off);
        u32 o2 = __shfl_xor(a2, off);
        merge3(a0, a1, a2, o0, o1, o2);
    }
    if (sub == 0) {
        const int l0 = (int)(a0 & 0xFFFFu) / CLASS_SIZE;
        const int l1 = (int)(a1 & 0xFFFFu) / CLASS_SIZE;
        const int l2 = (int)(a2 & 0xFFFFu) / CLASS_SIZE;
        int winner;
        if (l0 == l1 || l0 == l2)      winner = l0;
        else if (l1 == l2)             winner = l1;
        else winner = min(l0, min(l1, l2));
        out[t] = winner;
    }
}

// ======================= validated R5 fallback path ========================
#define TT          8
#define NCHUNK      4
#define CHUNK_ROWS  (NUM_TRAIN / NCHUNK)

__device__ __forceinline__ void insert3_minmax(u32& k0, u32& k1, u32& k2, u32 key) {
    u32 m0 = min(k0, key);
    u32 m1 = min(k1, max(k0, key));
    u32 m2 = min(k2, max(k1, key));
    k0 = m0; k1 = m1; k2 = m2;
}

__global__ void pack_kernel(const int* __restrict__ train,
                            const int* __restrict__ test,
                            u64* __restrict__ packed) {
    int wave = (blockIdx.x * blockDim.x + threadIdx.x) >> 6;
    int lane = threadIdx.x & 63;
    const int* src = (wave < NUM_TRAIN)
                       ? (train + (size_t)wave * 256)
                       : (test + (size_t)(wave - NUM_TRAIN) * 256);
    int4 v = *reinterpret_cast<const int4*>(src + lane * 4);
    u64 b0 = __ballot(v.x & 1);
    u64 b1 = __ballot(v.y & 1);
    u64 b2 = __ballot(v.z & 1);
    u64 b3 = __ballot(v.w & 1);
    if (lane == 0) {
        u64* dst = packed + (size_t)wave * 4;
        dst[0] = b0; dst[1] = b1; dst[2] = b2; dst[3] = b3;
    }
}

__global__ __launch_bounds__(256) void knn_kernel(const u32* __restrict__ packed,
                                                  u32* __restrict__ partial) {
    const int g    = blockIdx.x >> 2;
    const int c    = blockIdx.x & 3;
    const int tid  = threadIdx.x;
    const int base = g * TT;
    const uint4* rows  = (const uint4*)packed;
    const u32*  testp  = packed + (size_t)NUM_TRAIN * 8;

    u32 te[TT][8];
    #pragma unroll
    for (int s = 0; s < TT; ++s) {
        const u32* p = testp + (size_t)(base + s) * 8;
        #pragma unroll
        for (int j = 0; j < 8; ++j) te[s][j] = p[j];
    }
    u32 k0[TT], k1[TT], k2[TT];
    #pragma unroll
    for (int s = 0; s < TT; ++s) { k0[s] = k1[s] = k2[s] = 0x7FFFFFFFu; }

    const int start = c * CHUNK_ROWS;
    const int end   = start + CHUNK_ROWS;
    for (int r = start + tid; r < end; r += 256) {
        uint4 a0 = rows[(size_t)r * 2];
        uint4 a1 = rows[(size_t)r * 2 + 1];
        #pragma unroll
        for (int s = 0; s < TT; ++s) {
            int d = __popc(a0.x ^ te[s][0]);
            d += __popc(a0.y ^ te[s][1]);
            d += __popc(a0.z ^ te[s][2]);
            d += __popc(a0.w ^ te[s][3]);
            d += __popc(a1.x ^ te[s][4]);
            d += __popc(a1.y ^ te[s][5]);
            d += __popc(a1.z ^ te[s][6]);
            d += __popc(a1.w ^ te[s][7]);
            u32 key = ((u32)d << 16) | (u32)r;
            insert3_minmax(k0[s], k1[s], k2[s], key);
        }
    }
    #pragma unroll
    for (int s = 0; s < TT; ++s) {
        for (int off = 1; off < 64; off <<= 1) {
            u32 o0 = __shfl_xor(k0[s], off);
            u32 o1 = __shfl_xor(k1[s], off);
            u32 o2 = __shfl_xor(k2[s], off);
            merge3(k0[s], k1[s], k2[s], o0, o1, o2);
        }
    }
    __shared__ u32 red[4][TT][3];
    const int wave = tid >> 6, lane = tid & 63;
    if (lane == 0) {
        #pragma unroll
        for (int s = 0; s < TT; ++s) {
            red[wave][s][0] = k0[s];
            red[wave][s][1] = k1[s];
            red[wave][s][2] = k2[s];
        }
    }
    __syncthreads();
    if (tid < TT) {
        const int s = tid;
        u32 a0 = red[0][s][0], a1 = red[0][s][1], a2 = red[0][s][2];
        #pragma unroll
        for (int w = 1; w < 4; ++w)
            merge3(a0, a1, a2, red[w][s][0], red[w][s][1], red[w][s][2]);
        u32* dst = partial + ((size_t)(base + s) * NCHUNK + c) * 3;
        dst[0] = a0; dst[1] = a1; dst[2] = a2;
    }
}

__global__ __launch_bounds__(256) void merge_kernel(const u32* __restrict__ partial,
                                                    int* __restrict__ out) {
    int t = blockIdx.x * blockDim.x + threadIdx.x;
    if (t >= NUM_TEST) return;
    const u32* p = partial + (size_t)t * NCHUNK * 3;
    u32 a0 = p[0], a1 = p[1], a2 = p[2];
    #pragma unroll
    for (int c = 1; c < NCHUNK; ++c)
        merge3(a0, a1, a2, p[c * 3 + 0], p[c * 3 + 1], p[c * 3 + 2]);
    const int l0 = (int)(a0 & 0xFFFFu) / CLASS_SIZE;
    const int l1 = (int)(a1 & 0xFFFFu) / CLASS_SIZE;
    const int l2 = (int)(a2 & 0xFFFFu) / CLASS_SIZE;
    int winner;
    if (l0 == l1 || l0 == l2)      winner = l0;
    else if (l1 == l2)             winner = l1;
    else winner = min(l0, min(l1, l2));
    out[t] = winner;
}
// ===========================================================================

extern "C" void kernel_launch(void* const* d_in, const int* in_sizes, int n_in,
                              void* d_out, int out_size, void* d_ws, size_t ws_size,
                              hipStream_t stream) {
    const int* train = (const int*)d_in[0];
    const int* test  = (const int*)d_in[1];
    int* out = (int*)d_out;

    if (ws_size >= WS_NEED(112)) {
        char* train_swz = (char*)d_ws;
        char* test_i8   = (char*)d_ws + OFF_TEST;
        int*  tesum     = (int*)((char*)d_ws + OFF_TESUM);
        u32*  partial   = (u32*)((char*)d_ws + OFF_PART);

        pack_all<<<(TRAIN_PAD + NUM_TEST) / 4, 256, 0, stream>>>(train, test,
                                                                 train_swz, test_i8, tesum);
        mfma_knn<112><<<16 * 112, 256, 0, stream>>>(train_swz, test_i8, tesum, partial);
        vote_knn16<112><<<(NUM_TEST * 16) / 256, 256, 0, stream>>>(partial, out);
    } else {
        // validated R5 path (1.93 MB ws)
        u64* packed = (u64*)d_ws;
        u32* partial = (u32*)((char*)d_ws + (size_t)(NUM_TRAIN + NUM_TEST) * 4 * sizeof(u64));
        const int total_rows = NUM_TRAIN + NUM_TEST;
        pack_kernel<<<total_rows / 4, 256, 0, stream>>>(train, test, packed);
        knn_kernel<<<(NUM_TEST / TT) * NCHUNK, 256, 0, stream>>>((const u32*)packed, partial);
        merge_kernel<<<(NUM_TEST + 255) / 256, 256, 0, stream>>>(partial, out);
    }
}

// Round 23
// 77.950 us; speedup vs baseline: 1.0239x; 1.0239x over previous
//
#include <hip/hip_runtime.h>
#include <stdint.h>

typedef unsigned long long u64;
typedef unsigned int u32;
typedef int v4i  __attribute__((ext_vector_type(4)));
typedef int v16i __attribute__((ext_vector_type(16)));

#define NUM_TRAIN   50000
#define NUM_TEST    4096
#define CLASS_SIZE  5000
#define TRAIN_PAD   50176              // 1568 tiles of 32 rows
#define TOT_TILES   1568

// ws layout: train_i8 | test_i8 | te_sum | partial[c][col]
#define SZ_TRAIN   ((size_t)TRAIN_PAD * 256)          // 12,845,056
#define SZ_TEST    ((size_t)NUM_TEST * 256)           //  1,048,576
#define SZ_TESUM   ((size_t)NUM_TEST * 4)             //     16,384
#define OFF_TEST   (SZ_TRAIN)
#define OFF_TESUM  (OFF_TEST + SZ_TEST)
#define OFF_PART   (OFF_TESUM + SZ_TESUM)             // 13,910,016
#define WS_NEED(NCH) (OFF_PART + (size_t)NUM_TEST * (NCH) * 3 * 4)

// ---------------------------------------------------------------------------
// Top-3 primitives. key = (dist<<16)+idx encodes the reference
// (dist asc, then smaller index) tie-break exactly (validated R2..R22).
// insert3 via v_med3_u32 (3 VALU) — validated on-device R15..R22.
// ---------------------------------------------------------------------------
__device__ __forceinline__ void insert3(u32& k0, u32& k1, u32& k2, u32 key) {
    u32 m1, m2;
    asm("v_med3_u32 %0, %1, %2, %3" : "=v"(m1) : "v"(k0), "v"(k1), "v"(key));
    asm("v_med3_u32 %0, %1, %2, %3" : "=v"(m2) : "v"(k1), "v"(k2), "v"(key));
    k0 = min(k0, key);
    k1 = m1; k2 = m2;
}
__device__ __forceinline__ void merge3(u32& a0, u32& a1, u32& a2,
                                       u32 b0, u32 b1, u32 b2) {
    u32 hi0 = max(a0, b0);
    u32 lo1 = min(a1, b1);
    u32 c0  = min(a0, b0);
    u32 c1  = min(hi0, lo1);
    u32 c2  = min(max(lo1, hi0), min(a2, b2));
    a0 = c0; a1 = c1; a2 = c2;
}
__device__ __forceinline__ int wave_sum(int s) {
    #pragma unroll
    for (int off = 1; off < 64; off <<= 1) s += __shfl_xor(s, off);
    return s;
}

// ---------------------------------------------------------------------------
// pack_all (fused, validated R15..R21): wave id r < TRAIN_PAD -> train row
// (byte=bit, pad rows zero); else test row (byte = 1-2*bit, +tesum).
// ---------------------------------------------------------------------------
__global__ __launch_bounds__(256) void pack_all(const int* __restrict__ train,
                                                const int* __restrict__ test,
                                                char* __restrict__ dstA,
                                                char* __restrict__ dstB,
                                                int* __restrict__ tesum) {
    int r    = (blockIdx.x * 256 + threadIdx.x) >> 6;
    int lane = threadIdx.x & 63;
    if (r < TRAIN_PAD) {
        int4 v = make_int4(0, 0, 0, 0);
        if (r < NUM_TRAIN)
            v = *reinterpret_cast<const int4*>(train + (size_t)r * 256 + lane * 4);
        u32 w = (u32)(v.x & 1) | ((u32)(v.y & 1) << 8)
              | ((u32)(v.z & 1) << 16) | ((u32)(v.w & 1) << 24);
        *reinterpret_cast<u32*>(dstA + (size_t)r * 256 + lane * 4) = w;
    } else {
        int rt = r - TRAIN_PAD;
        int4 v = *reinterpret_cast<const int4*>(test + (size_t)rt * 256 + lane * 4);
        u32 w = (u32)((1 - 2 * v.x) & 0xFF) | ((u32)((1 - 2 * v.y) & 0xFF) << 8)
              | ((u32)((1 - 2 * v.z) & 0xFF) << 16) | ((u32)((1 - 2 * v.w) & 0xFF) << 24);
        *reinterpret_cast<u32*>(dstB + (size_t)rt * 256 + lane * 4) = w;
        int total = wave_sum(v.x + v.y + v.z + v.w);
        if (lane == 0) tesum[rt] = total;
    }
}

// ---------------------------------------------------------------------------
// mfma_knn (R23 = R21 body + UPFRONT A-fragment loads):
//   The only change vs R21 (twice-validated 69.5-69.7 us): all 8 af
//   fragments are ds_read into registers BEFORE the MFMA chain (32 VGPRs,
//   static indexing), so the 8 LDS reads issue back-to-back (pipelined)
//   instead of load->wait->MFMA per kk (8 serialized ~120-cyc latencies).
//   - R10-validated conflict-free LDS layout; lds[2][8192]; 2-phase dbuf
//     loop, ONE barrier per tile; reg-staged T14 split; med3 insert3;
//     setprio around MFMA; transposed partial [c][col].
// acc = tr_sum - 2*inner; dist = acc + te_sum folded into the key base.
// ---------------------------------------------------------------------------
template<int NCH>
__global__ __launch_bounds__(256) void mfma_knn(const char* __restrict__ A,
                                                const char* __restrict__ Bt,
                                                const int* __restrict__ tesum,
                                                u32* __restrict__ partial) {
    constexpr int TILES  = TOT_TILES / NCH;    // 14 (NCH=112); must be EVEN
    constexpr int CHROWS = TRAIN_PAD / NCH;    // 448
    static_assert((TILES & 1) == 0, "2-phase dbuf loop needs even TILES");
    const int cg   = blockIdx.x / NCH;
    const int c    = blockIdx.x % NCH;
    const int tid  = threadIdx.x;
    const int wid  = tid >> 6;
    const int lane = tid & 63;
    const int a    = lane & 31;                // A-row within tile / B-col lane
    const int kh   = lane >> 5;                // K-half

    // Two B-fragment sets: this wave's 64 test cols, 8 K-steps, in registers.
    const int col0 = cg * 256 + wid * 64 + a;
    const int col1 = col0 + 32;
    v4i bf0[8], bf1[8];
    {
        const char* bp0 = Bt + (size_t)col0 * 256 + kh * 16;
        const char* bp1 = Bt + (size_t)col1 * 256 + kh * 16;
        #pragma unroll
        for (int kk = 0; kk < 8; ++kk) {
            bf0[kk] = *reinterpret_cast<const v4i*>(bp0 + kk * 32);
            bf1[kk] = *reinterpret_cast<const v4i*>(bp1 + kk * 32);
        }
    }
    const u32 base0 = ((u32)tesum[col0] << 16);   // te_sum folded into key
    const u32 base1 = ((u32)tesum[col1] << 16);

    __shared__ char lds[2][8192];
    char* rd[8];                               // buf0 read addrs per kk
    #pragma unroll
    for (int kk = 0; kk < 8; ++kk)
        rd[kk] = &lds[0][kk * 1024 + kh * 512 + ((a ^ kk) & 31) * 16];

    // staging: thread t covers row grow, bytes [gc*32, +32) (coalesced t*32)
    const int grow = tid >> 3, gc = tid & 7;
    const char* gsrc0 = A + (size_t)c * CHROWS * 256 + grow * 256 + gc * 32;
    char* w0 = &lds[0][gc * 1024 +       ((grow ^ gc) & 31) * 16];   // kh=0
    char* w1 = &lds[0][gc * 1024 + 512 + ((grow ^ gc) & 31) * 16];   // kh=1

    u32 p00 = 0x7FFFFFFFu, p01 = 0x7FFFFFFFu, p02 = 0x7FFFFFFFu;
    u32 p10 = 0x7FFFFFFFu, p11 = 0x7FFFFFFFu, p12 = 0x7FFFFFFFu;

    // prologue: stage tile 0 into buf 0
    {
        uint4 s0 = *reinterpret_cast<const uint4*>(gsrc0);
        uint4 s1 = *reinterpret_cast<const uint4*>(gsrc0 + 16);
        *reinterpret_cast<uint4*>(w0) = s0;
        *reinterpret_cast<uint4*>(w1) = s1;
    }
    __syncthreads();

// Tile TT: issue loads for TT+1 (T14), ds_read ALL 8 A-fragments upfront,
// run the 16-MFMA chain clean (setprio-wrapped), insert epilogue,
// ds_write to buf WB, ONE barrier.
#define TILE_STEP(TT, RB, WB)                                                 \
    {                                                                         \
        const int tt = (TT);                                                  \
        uint4 s0, s1;                                                         \
        const bool pf = (tt + 1 < TILES);                                     \
        if (pf) {                                                             \
            const char* g = gsrc0 + (size_t)(tt + 1) * 8192;                  \
            s0 = *reinterpret_cast<const uint4*>(g);                          \
            s1 = *reinterpret_cast<const uint4*>(g + 16);                     \
        }                                                                     \
        v4i af[8];                                                            \
        _Pragma("unroll")                                                     \
        for (int kk = 0; kk < 8; ++kk)                                        \
            af[kk] = *reinterpret_cast<const v4i*>(rd[kk] + (RB) * 8192);     \
        v16i acc0 = {0,0,0,0,0,0,0,0,0,0,0,0,0,0,0,0};                        \
        v16i acc1 = {0,0,0,0,0,0,0,0,0,0,0,0,0,0,0,0};                        \
        __builtin_amdgcn_s_setprio(1);                                        \
        _Pragma("unroll")                                                     \
        for (int kk = 0; kk < 8; ++kk) {                                      \
            acc0 = __builtin_amdgcn_mfma_i32_32x32x32_i8(af[kk], bf0[kk], acc0, 0, 0, 0); \
            acc1 = __builtin_amdgcn_mfma_i32_32x32x32_i8(af[kk], bf1[kk], acc1, 0, 0, 0); \
        }                                                                     \
        __builtin_amdgcn_s_setprio(0);                                        \
        const int tbase = c * CHROWS + tt * 32;                               \
        const u32 kb0 = base0 + (u32)(tbase + 4 * kh);                        \
        const u32 kb1 = base1 + (u32)(tbase + 4 * kh);                        \
        if (tbase + 32 <= NUM_TRAIN) {                                        \
            _Pragma("unroll")                                                 \
            for (int g = 0; g < 16; ++g) {                                    \
                const int row = (g & 3) + 8 * (g >> 2);                       \
                insert3(p00, p01, p02, ((u32)acc0[g] << 16) + kb0 + (u32)row);\
                insert3(p10, p11, p12, ((u32)acc1[g] << 16) + kb1 + (u32)row);\
            }                                                                 \
        } else {                                                              \
            _Pragma("unroll")                                                 \
            for (int g = 0; g < 16; ++g) {                                    \
                const int row = (g & 3) + 8 * (g >> 2);                       \
                const int idx = tbase + 4 * kh + row;                         \
                u32 key0 = (idx < NUM_TRAIN)                                  \
                    ? (((u32)acc0[g] << 16) + kb0 + (u32)row) : 0xFFFFFFFFu;  \
                u32 key1 = (idx < NUM_TRAIN)                                  \
                    ? (((u32)acc1[g] << 16) + kb1 + (u32)row) : 0xFFFFFFFFu;  \
                insert3(p00, p01, p02, key0);                                 \
                insert3(p10, p11, p12, key1);                                 \
            }                                                                 \
        }                                                                     \
        if (pf) {                                                             \
            *reinterpret_cast<uint4*>(w0 + (WB) * 8192) = s0;                 \
            *reinterpret_cast<uint4*>(w1 + (WB) * 8192) = s1;                 \
        }                                                                     \
        __syncthreads();                                                      \
    }

    #pragma unroll 1
    for (int t = 0; t < TILES; t += 2) {
        TILE_STEP(t,     0, 1);        // compute buf0, stage tile t+1 -> buf1
        TILE_STEP(t + 1, 1, 0);        // compute buf1, stage tile t+2 -> buf0
    }
#undef TILE_STEP

    // lanes l / l+32 hold complementary row-halves of the same test col
    u32 o0, o1, o2;
    o0 = __shfl_xor(p00, 32); o1 = __shfl_xor(p01, 32); o2 = __shfl_xor(p02, 32);
    merge3(p00, p01, p02, o0, o1, o2);
    o0 = __shfl_xor(p10, 32); o1 = __shfl_xor(p11, 32); o2 = __shfl_xor(p12, 32);
    merge3(p10, p11, p12, o0, o1, o2);
    if (kh == 0) {
        // transposed layout: consecutive cols -> consecutive 12B (coalesced)
        u32* d0 = partial + ((size_t)c * NUM_TEST + col0) * 3;
        d0[0] = p00; d0[1] = p01; d0[2] = p02;
        u32* d1 = partial + ((size_t)c * NUM_TEST + col1) * 3;
        d1[0] = p10; d1[1] = p11; d1[2] = p12;
    }
}

// ---------------------------------------------------------------------------
// vote_knn16 (validated R21): 16 lanes per sample; each merges NCH/16 chunks,
// then 4 __shfl_xor merge3 steps. Majority vote, argmax-first-max ties.
// ---------------------------------------------------------------------------
template<int NCH>
__global__ __launch_bounds__(256) void vote_knn16(const u32* __restrict__ partial,
                                                  int* __restrict__ out) {
    static_assert(NCH % 16 == 0, "16-lane vote needs NCH % 16 == 0");
    const int gid = blockIdx.x * 256 + threadIdx.x;
    const int t   = gid >> 4;          // sample
    const int sub = gid & 15;          // 16-lane group index (= lane & 15)
    if (t >= NUM_TEST) return;
    u32 a0 = 0x7FFFFFFFu, a1 = 0x7FFFFFFFu, a2 = 0x7FFFFFFFu;
    #pragma unroll
    for (int j = 0; j < NCH / 16; ++j) {
        const int c = sub + 16 * j;
        const u32* q = partial + ((size_t)c * NUM_TEST + t) * 3;
        merge3(a0, a1, a2, q[0], q[1], q[2]);
    }
    #pragma unroll
    for (int off = 1; off < 16; off <<= 1) {
        u32 o0 = __shfl_xor(a0, off);
        u32 o1 = __shfl_xor(a1, off);
        u32 o2 = __shfl_xor(a2, off);
        merge3(a0, a1, a2, o0, o1, o2);
    }
    if (sub == 0) {
        const int l0 = (int)(a0 & 0xFFFFu) / CLASS_SIZE;
        const int l1 = (int)(a1 & 0xFFFFu) / CLASS_SIZE;
        const int l2 = (int)(a2 & 0xFFFFu) / CLASS_SIZE;
        int winner;
        if (l0 == l1 || l0 == l2)      winner = l0;
        else if (l1 == l2)             winner = l1;
        else winner = min(l0, min(l1, l2));
        out[t] = winner;
    }
}

// ======================= validated R5 fallback path ========================
#define TT          8
#define NCHUNK      4
#define CHUNK_ROWS  (NUM_TRAIN / NCHUNK)

__device__ __forceinline__ void insert3_minmax(u32& k0, u32& k1, u32& k2, u32 key) {
    u32 m0 = min(k0, key);
    u32 m1 = min(k1, max(k0, key));
    u32 m2 = min(k2, max(k1, key));
    k0 = m0; k1 = m1; k2 = m2;
}

__global__ void pack_kernel(const int* __restrict__ train,
                            const int* __restrict__ test,
                            u64* __restrict__ packed) {
    int wave = (blockIdx.x * blockDim.x + threadIdx.x) >> 6;
    int lane = threadIdx.x & 63;
    const int* src = (wave < NUM_TRAIN)
                       ? (train + (size_t)wave * 256)
                       : (test + (size_t)(wave - NUM_TRAIN) * 256);
    int4 v = *reinterpret_cast<const int4*>(src + lane * 4);
    u64 b0 = __ballot(v.x & 1);
    u64 b1 = __ballot(v.y & 1);
    u64 b2 = __ballot(v.z & 1);
    u64 b3 = __ballot(v.w & 1);
    if (lane == 0) {
        u64* dst = packed + (size_t)wave * 4;
        dst[0] = b0; dst[1] = b1; dst[2] = b2; dst[3] = b3;
    }
}

__global__ __launch_bounds__(256) void knn_kernel(const u32* __restrict__ packed,
                                                  u32* __restrict__ partial) {
    const int g    = blockIdx.x >> 2;
    const int c    = blockIdx.x & 3;
    const int tid  = threadIdx.x;
    const int base = g * TT;
    const uint4* rows  = (const uint4*)packed;
    const u32*  testp  = packed + (size_t)NUM_TRAIN * 8;

    u32 te[TT][8];
    #pragma unroll
    for (int s = 0; s < TT; ++s) {
        const u32* p = testp + (size_t)(base + s) * 8;
        #pragma unroll
        for (int j = 0; j < 8; ++j) te[s][j] = p[j];
    }
    u32 k0[TT], k1[TT], k2[TT];
    #pragma unroll
    for (int s = 0; s < TT; ++s) { k0[s] = k1[s] = k2[s] = 0x7FFFFFFFu; }

    const int start = c * CHUNK_ROWS;
    const int end   = start + CHUNK_ROWS;
    for (int r = start + tid; r < end; r += 256) {
        uint4 a0 = rows[(size_t)r * 2];
        uint4 a1 = rows[(size_t)r * 2 + 1];
        #pragma unroll
        for (int s = 0; s < TT; ++s) {
            int d = __popc(a0.x ^ te[s][0]);
            d += __popc(a0.y ^ te[s][1]);
            d += __popc(a0.z ^ te[s][2]);
            d += __popc(a0.w ^ te[s][3]);
            d += __popc(a1.x ^ te[s][4]);
            d += __popc(a1.y ^ te[s][5]);
            d += __popc(a1.z ^ te[s][6]);
            d += __popc(a1.w ^ te[s][7]);
            u32 key = ((u32)d << 16) | (u32)r;
            insert3_minmax(k0[s], k1[s], k2[s], key);
        }
    }
    #pragma unroll
    for (int s = 0; s < TT; ++s) {
        for (int off = 1; off < 64; off <<= 1) {
            u32 o0 = __shfl_xor(k0[s], off);
            u32 o1 = __shfl_xor(k1[s], off);
            u32 o2 = __shfl_xor(k2[s], off);
            merge3(k0[s], k1[s], k2[s], o0, o1, o2);
        }
    }
    __shared__ u32 red[4][TT][3];
    const int wave = tid >> 6, lane = tid & 63;
    if (lane == 0) {
        #pragma unroll
        for (int s = 0; s < TT; ++s) {
            red[wave][s][0] = k0[s];
            red[wave][s][1] = k1[s];
            red[wave][s][2] = k2[s];
        }
    }
    __syncthreads();
    if (tid < TT) {
        const int s = tid;
        u32 a0 = red[0][s][0], a1 = red[0][s][1], a2 = red[0][s][2];
        #pragma unroll
        for (int w = 1; w < 4; ++w)
            merge3(a0, a1, a2, red[w][s][0], red[w][s][1], red[w][s][2]);
        u32* dst = partial + ((size_t)(base + s) * NCHUNK + c) * 3;
        dst[0] = a0; dst[1] = a1; dst[2] = a2;
    }
}

__global__ __launch_bounds__(256) void merge_kernel(const u32* __restrict__ partial,
                                                    int* __restrict__ out) {
    int t = blockIdx.x * blockDim.x + threadIdx.x;
    if (t >= NUM_TEST) return;
    const u32* p = partial + (size_t)t * NCHUNK * 3;
    u32 a0 = p[0], a1 = p[1], a2 = p[2];
    #pragma unroll
    for (int c = 1; c < NCHUNK; ++c)
        merge3(a0, a1, a2, p[c * 3 + 0], p[c * 3 + 1], p[c * 3 + 2]);
    const int l0 = (int)(a0 & 0xFFFFu) / CLASS_SIZE;
    const int l1 = (int)(a1 & 0xFFFFu) / CLASS_SIZE;
    const int l2 = (int)(a2 & 0xFFFFu) / CLASS_SIZE;
    int winner;
    if (l0 == l1 || l0 == l2)      winner = l0;
    else if (l1 == l2)             winner = l1;
    else winner = min(l0, min(l1, l2));
    out[t] = winner;
}
// ===========================================================================

extern "C" void kernel_launch(void* const* d_in, const int* in_sizes, int n_in,
                              void* d_out, int out_size, void* d_ws, size_t ws_size,
                              hipStream_t stream) {
    const int* train = (const int*)d_in[0];
    const int* test  = (const int*)d_in[1];
    int* out = (int*)d_out;

    if (ws_size >= WS_NEED(112)) {
        char* train_i8 = (char*)d_ws;
        char* test_i8  = (char*)d_ws + OFF_TEST;
        int*  tesum    = (int*)((char*)d_ws + OFF_TESUM);
        u32*  partial  = (u32*)((char*)d_ws + OFF_PART);

        pack_all<<<(TRAIN_PAD + NUM_TEST) / 4, 256, 0, stream>>>(train, test,
                                                                 train_i8, test_i8, tesum);
        mfma_knn<112><<<16 * 112, 256, 0, stream>>>(train_i8, test_i8, tesum, partial);
        vote_knn16<112><<<(NUM_TEST * 16) / 256, 256, 0, stream>>>(partial, out);
    } else {
        // validated R5 path (1.93 MB ws)
        u64* packed = (u64*)d_ws;
        u32* partial = (u32*)((char*)d_ws + (size_t)(NUM_TRAIN + NUM_TEST) * 4 * sizeof(u64));
        const int total_rows = NUM_TRAIN + NUM_TEST;
        pack_kernel<<<total_rows / 4, 256, 0, stream>>>(train, test, packed);
        knn_kernel<<<(NUM_TEST / TT) * NCHUNK, 256, 0, stream>>>((const u32*)packed, partial);
        merge_kernel<<<(NUM_TEST + 255) / 256, 256, 0, stream>>>(partial, out);
    }
}